// Round 20
// baseline (2559.071 us; speedup 1.0000x reference)
//
#include <hip/hip_runtime.h>
#include <math.h>

#define BB 16
#define LL 128
#define HH 1024
#define EE 512
#define VV 32000
#define G3 3072
#define NBLK 256

typedef __fp16 h2t __attribute__((ext_vector_type(2)));
typedef unsigned int uint_;

__device__ __forceinline__ float sigmoidf_(float x){ return 1.0f/(1.0f+expf(-x)); }

__device__ __forceinline__ uint_ pk16(float a, float b){
  h2t h = __builtin_amdgcn_cvt_pkrtz(a, b);
  return __builtin_bit_cast(uint_, h);
}
__device__ __forceinline__ void dot2(float& acc, uint_ w, uint_ h){
  asm("v_dot2_f32_f16 %0, %1, %2, %0" : "+v"(acc) : "v"(w), "v"(h));
}
__device__ __forceinline__ float red64(float v){
  v += __shfl_xor(v, 1, 64); v += __shfl_xor(v, 2, 64);
  v += __shfl_xor(v, 4, 64); v += __shfl_xor(v, 8, 64);
  v += __shfl_xor(v, 16, 64); v += __shfl_xor(v, 32, 64);
  return v;
}
__device__ __forceinline__ float red32(float v){
  v += __shfl_xor(v, 1, 64); v += __shfl_xor(v, 2, 64);
  v += __shfl_xor(v, 4, 64); v += __shfl_xor(v, 8, 64);
  v += __shfl_xor(v, 16, 64);
  return v;
}

// Encoder GEMM with inline token lookup
__global__ __launch_bounds__(256) void k_gemm_enc(const float* __restrict__ emb, const int* __restrict__ inp,
                       const float* __restrict__ Bm, const float* __restrict__ bias,
                       float* __restrict__ C){
  __shared__ float As[32*EE];
  const int tid = threadIdx.x;
  const int r0 = blockIdx.x*32;
  const int c  = blockIdx.y*512 + (tid<<1);
  for (int i = tid; i < 32*EE; i += 256){
    int rr = i >> 9;
    int row = r0 + rr;
    int l = row >> 4, bb = row & 15;
    int tok = inp[bb*LL + l];
    int kk = i & 511;
    As[i] = emb[(size_t)tok*EE + kk];
  }
  __syncthreads();
  float2 acc[32];
  #pragma unroll
  for (int r=0;r<32;r++){ acc[r].x=0.f; acc[r].y=0.f; }
  for (int k=0;k<EE;k++){
    const float2 w = *(const float2*)(Bm + (size_t)k*HH + c);
    #pragma unroll
    for (int r=0;r<32;r++){
      float a = As[(r<<9)+k];
      acc[r].x = fmaf(a,w.x,acc[r].x);
      acc[r].y = fmaf(a,w.y,acc[r].y);
    }
  }
  const float2 bv = *(const float2*)(bias + c);
  #pragma unroll
  for (int r=0;r<32;r++){
    float x = tanhf(acc[r].x + bv.x), y = tanhf(acc[r].y + bv.y);
    *(float2*)(C + (size_t)(r0+r)*HH + c) = make_float2(x,y);
  }
}

// v12: R19 skeleton (512 thr, A-first, busy-poll aggregator barrier) with
// fp16 packed weights in LDS + v_dot2_f32_f16 MACs (fp32 accumulate).
__global__ __launch_bounds__(512,1) void k_chains(
    const float* enclast, float* H0all, float* H1all,
    const float* __restrict__ Whh0, const float* __restrict__ Whh1,
    const float* __restrict__ Wih0, const float* __restrict__ Wih1,
    const float* __restrict__ emb,
    const float* __restrict__ bih0, const float* __restrict__ bhh0,
    const float* __restrict__ bhh1, const float* __restrict__ bih1,
    int* flags, int* go)
{
  __shared__ uint_ w0l[12][512];   // Whh0 fp16 pairs (prologue: Wih0 scratch)
  __shared__ uint_ w1l[12][512];   // Whh1
  __shared__ uint_ wil[12][512];   // Wih1
  __shared__ float gxbuf[16*12];
  const int tid  = threadIdx.x;
  const int jb   = blockIdx.x << 2;
  const int waveid = tid >> 6;
  const int cgA = waveid >> 2;
  const int bgA = waveid & 3;
  const int kgA = tid & 63;
  const int koffA = kgA << 2;
  const int b0A = bgA << 2;
  const int cgB = waveid >> 1;
  const int bgB = ((waveid & 1) << 1) | ((tid >> 5) & 1);
  const int kgB = tid & 31;
  const int koffB = kgB << 2;
  const int b0B = bgB << 2;
  const int mB  = cgB >> 1;

  const bool pwA = (kgA < 8);
  const int  jlA = (cgA << 1) + (kgA & 1);
  const int  jpA = jb + jlA;
  const int  biA = (kgA >> 1) & 3;
  const int  bA  = b0A + biA;
  const bool pwB = (cgB >= 2) && (kgB < 8);
  const int  jlB = ((cgB & 1) << 1) + (kgB & 1);
  const int  jpB = jb + jlB;
  const int  biB = (kgB >> 1) & 3;
  const int  bB  = b0B + biB;

  // ---- prologue 1: gx0 via Wih0 (fp16) staged into w0l scratch ----
  float g0r=0.f, g0z=0.f, g0n=0.f;
  {
    for (int idx = tid; idx < 768; idx += 512){
      int g = idx >> 8, kp = idx & 255, k = kp << 1;
      float4 a0 = *(const float4*)(Wih0 + (size_t)k*G3 + g*1024 + jb);
      float4 a1 = *(const float4*)(Wih0 + (size_t)(k+1)*G3 + g*1024 + jb);
      w0l[g*4+0][kp] = pk16(a0.x, a1.x);
      w0l[g*4+1][kp] = pk16(a0.y, a1.y);
      w0l[g*4+2][kp] = pk16(a0.z, a1.z);
      w0l[g*4+3][kp] = pk16(a0.w, a1.w);
    }
    __syncthreads();
    const float* e1 = emb + EE;
    float ag[6];
    #pragma unroll
    for (int cl=0;cl<6;cl++) ag[cl]=0.f;
    #pragma unroll
    for (int u=0;u<2;u++){
      const int k0 = u*256 + koffA, kp0 = k0 >> 1;
      float4 e = *(const float4*)(e1 + k0);
      uint_ e01 = pk16(e.x, e.y), e23 = pk16(e.z, e.w);
      #pragma unroll
      for (int cl=0;cl<6;cl++){
        const int gc = ((cl>>1)<<2) + (cgA<<1) + (cl&1);
        dot2(ag[cl], w0l[gc][kp0],   e01);
        dot2(ag[cl], w0l[gc][kp0+1], e23);
      }
    }
    #pragma unroll
    for (int cl=0;cl<6;cl++) ag[cl] = red64(ag[cl]);
    if (pwA){
      const int jj = kgA & 1;
      g0r = (jj ? ag[1] : ag[0]) + bih0[jpA];
      g0z = (jj ? ag[3] : ag[2]) + bih0[1024+jpA];
      g0n = (jj ? ag[5] : ag[4]) + bih0[2048+jpA];
    }
    __syncthreads();
  }

  // ---- prologue 2: stage Whh0 / Whh1 / Wih1 as fp16 pairs ----
  for (int idx = tid; idx < 1536; idx += 512){
    int g = idx >> 9, kp = idx & 511, k = kp << 1;
    {
      float4 a0 = *(const float4*)(Whh0 + (size_t)k*G3 + g*1024 + jb);
      float4 a1 = *(const float4*)(Whh0 + (size_t)(k+1)*G3 + g*1024 + jb);
      w0l[g*4+0][kp] = pk16(a0.x, a1.x);
      w0l[g*4+1][kp] = pk16(a0.y, a1.y);
      w0l[g*4+2][kp] = pk16(a0.z, a1.z);
      w0l[g*4+3][kp] = pk16(a0.w, a1.w);
    }
    {
      float4 a0 = *(const float4*)(Whh1 + (size_t)k*G3 + g*1024 + jb);
      float4 a1 = *(const float4*)(Whh1 + (size_t)(k+1)*G3 + g*1024 + jb);
      w1l[g*4+0][kp] = pk16(a0.x, a1.x);
      w1l[g*4+1][kp] = pk16(a0.y, a1.y);
      w1l[g*4+2][kp] = pk16(a0.z, a1.z);
      w1l[g*4+3][kp] = pk16(a0.w, a1.w);
    }
    {
      float4 a0 = *(const float4*)(Wih1 + (size_t)k*G3 + g*1024 + jb);
      float4 a1 = *(const float4*)(Wih1 + (size_t)(k+1)*G3 + g*1024 + jb);
      wil[g*4+0][kp] = pk16(a0.x, a1.x);
      wil[g*4+1][kp] = pk16(a0.y, a1.y);
      wil[g*4+2][kp] = pk16(a0.z, a1.z);
      wil[g*4+3][kp] = pk16(a0.w, a1.w);
    }
  }
  float b0rA=0.f,b0zA=0.f,b0nA=0.f;
  if (pwA){ b0rA = bhh0[jpA]; b0zA = bhh0[1024+jpA]; b0nA = bhh0[2048+jpA]; }
  float birB=0.f,bizB=0.f,binB=0.f,b1rB=0.f,b1zB=0.f,b1nB=0.f;
  if (pwB){
    birB = bih1[jpB]; bizB = bih1[1024+jpB]; binB = bih1[2048+jpB];
    b1rB = bhh1[jpB]; b1zB = bhh1[1024+jpB]; b1nB = bhh1[2048+jpB];
  }
  __syncthreads();

  const int myflag = (int)blockIdx.x * 32;

  for (int t = 0; t <= LL; ++t){
    // ---- wait(t): block-0 aggregator + single go, busy polls ----
    if (t >= 1){
      if (blockIdx.x == 0){
        if (tid < 256){
          while (__hip_atomic_load(&flags[tid*32], __ATOMIC_RELAXED,
                                   __HIP_MEMORY_SCOPE_AGENT) < t) {}
        }
        __syncthreads();
        if (tid == 0)
          __hip_atomic_store(go, t, __ATOMIC_RELAXED, __HIP_MEMORY_SCOPE_AGENT);
      } else {
        if (tid == 0){
          while (__hip_atomic_load(go, __ATOMIC_RELAXED,
                                   __HIP_MEMORY_SCOPE_AGENT) < t) {}
        }
        __syncthreads();
      }
    }

    // ---- A(t): layer0 step t (first: stores drain under B) ----
    if (t < LL){
      const float* hp0 = (t==0) ? enclast : (H0all + (size_t)(t-1)*(BB*HH));
      float hprev0 = 0.f;
      if (pwA) hprev0 = hp0[(size_t)bA*HH + jpA];

      float acc0[6][4];
      #pragma unroll
      for (int cl=0;cl<6;cl++)
        #pragma unroll
        for (int bi=0;bi<4;bi++) acc0[cl][bi]=0.f;

      #pragma unroll
      for (int u=0;u<4;u++){
        const int k0 = u*256 + koffA, kp0 = k0 >> 1;
        uint_ hh[4][2];
        #pragma unroll
        for (int bi=0;bi<4;bi++){
          float4 hv = *(const float4*)(hp0 + (size_t)(b0A+bi)*HH + k0);
          hh[bi][0] = pk16(hv.x, hv.y);
          hh[bi][1] = pk16(hv.z, hv.w);
        }
        #pragma unroll
        for (int cl=0;cl<6;cl++){
          const int gc = ((cl>>1)<<2) + (cgA<<1) + (cl&1);
          const uint_ w01 = w0l[gc][kp0];
          const uint_ w23 = w0l[gc][kp0+1];
          #pragma unroll
          for (int bi=0;bi<4;bi++){
            dot2(acc0[cl][bi], w01, hh[bi][0]);
            dot2(acc0[cl][bi], w23, hh[bi][1]);
          }
        }
      }
      #pragma unroll
      for (int cl=0;cl<6;cl++)
        #pragma unroll
        for (int bi=0;bi<4;bi++) acc0[cl][bi] = red64(acc0[cl][bi]);

      if (pwA){
        float ghr=0.f, ghz=0.f, ghn=0.f;
        #pragma unroll
        for (int jj=0;jj<2;jj++)
          #pragma unroll
          for (int ii=0;ii<4;ii++){
            bool sel = ((kgA&1)==jj) & (biA==ii);
            ghr = sel ? acc0[jj][ii]   : ghr;
            ghz = sel ? acc0[2+jj][ii] : ghz;
            ghn = sel ? acc0[4+jj][ii] : ghn;
          }
        float r = sigmoidf_(g0r + ghr + b0rA);
        float z = sigmoidf_(g0z + ghz + b0zA);
        float n = tanhf    (g0n + r*(ghn + b0nA));
        float hnew = (1.f-z)*n + z*hprev0;
        __hip_atomic_store((int*)&H0all[(size_t)t*(BB*HH) + (size_t)bA*HH + jpA],
                           __float_as_int(hnew),
                           __ATOMIC_RELAXED, __HIP_MEMORY_SCOPE_AGENT);
      }
    }

    // ---- B(t): gx1 = h0[t-1]@Wih1 ; layer1 step t-1 ----
    if (t >= 1){
      const float* hp0 = H0all + (size_t)(t-1)*(BB*HH);
      const float* hp1 = (t==1) ? enclast : (H1all + (size_t)(t-2)*(BB*HH));
      const float* hr  = mB ? hp1 : hp0;
      float hprev1 = 0.f;
      if (pwB) hprev1 = hp1[(size_t)bB*HH + jpB];

      float accB[6][4];
      #pragma unroll
      for (int cl=0;cl<6;cl++)
        #pragma unroll
        for (int bi=0;bi<4;bi++) accB[cl][bi]=0.f;

      #pragma unroll
      for (int u=0;u<8;u++){
        const int k0 = u*128 + koffB, kp0 = k0 >> 1;
        uint_ hh[4][2];
        #pragma unroll
        for (int bi=0;bi<4;bi++){
          float4 hv = *(const float4*)(hr + (size_t)(b0B+bi)*HH + k0);
          hh[bi][0] = pk16(hv.x, hv.y);
          hh[bi][1] = pk16(hv.z, hv.w);
        }
        #pragma unroll
        for (int cl=0;cl<6;cl++){
          const int gc = ((cl>>1)<<2) + ((cgB&1)<<1) + (cl&1);
          const uint_ w01 = mB ? w1l[gc][kp0]   : wil[gc][kp0];
          const uint_ w23 = mB ? w1l[gc][kp0+1] : wil[gc][kp0+1];
          #pragma unroll
          for (int bi=0;bi<4;bi++){
            dot2(accB[cl][bi], w01, hh[bi][0]);
            dot2(accB[cl][bi], w23, hh[bi][1]);
          }
        }
      }
      #pragma unroll
      for (int cl=0;cl<6;cl++)
        #pragma unroll
        for (int bi=0;bi<4;bi++) accB[cl][bi] = red32(accB[cl][bi]);

      if (mB == 0){
        #pragma unroll
        for (int cl=0;cl<6;cl++){
          if (kgB == cl){
            const int g = cl >> 1;
            const int jl = ((cgB&1)<<1) + (cl&1);
            #pragma unroll
            for (int bi=0;bi<4;bi++)
              gxbuf[(b0B+bi)*12 + g*4 + jl] = accB[cl][bi];
          }
        }
      }
      __syncthreads();
      if (pwB){
        float ghr=0.f, ghz=0.f, ghn=0.f;
        #pragma unroll
        for (int jj=0;jj<2;jj++)
          #pragma unroll
          for (int ii=0;ii<4;ii++){
            bool sel = ((kgB&1)==jj) & (biB==ii);
            ghr = sel ? accB[jj][ii]   : ghr;
            ghz = sel ? accB[2+jj][ii] : ghz;
            ghn = sel ? accB[4+jj][ii] : ghn;
          }
        float gxr = gxbuf[bB*12 + 0*4 + jlB];
        float gxz = gxbuf[bB*12 + 1*4 + jlB];
        float gxn = gxbuf[bB*12 + 2*4 + jlB];
        float r = sigmoidf_(gxr + birB + ghr + b1rB);
        float z = sigmoidf_(gxz + bizB + ghz + b1zB);
        float n = tanhf    (gxn + binB + r*(ghn + b1nB));
        float hnew = (1.f-z)*n + z*hprev1;
        __hip_atomic_store((int*)&H1all[(size_t)(t-1)*(BB*HH) + (size_t)bB*HH + jpB],
                           __float_as_int(hnew),
                           __ATOMIC_RELAXED, __HIP_MEMORY_SCOPE_AGENT);
      }
    }

    if (t < LL){
      asm volatile("s_waitcnt vmcnt(0)" ::: "memory");
      __syncthreads();
      if (tid == 0)
        __hip_atomic_store(&flags[myflag], t+1,
                           __ATOMIC_RELAXED, __HIP_MEMORY_SCOPE_AGENT);
    }
  }
}

// Fused attention + gathered logit: ctx never leaves LDS.
__global__ __launch_bounds__(256) void k_attn_logit(const float* __restrict__ enc,
                       const float* __restrict__ H1,
                       const float* __restrict__ Wout, const float* __restrict__ bout,
                       const int* __restrict__ inp, const int* __restrict__ ts,
                       float* __restrict__ outp, float* __restrict__ bce){
  __shared__ float h1s[8][HH];
  __shared__ float ctxs[8][HH];
  __shared__ float sc[8][LL];
  __shared__ float part[2][8][LL];
  const int tid = threadIdx.x;
  const int s0 = blockIdx.x*8, b = blockIdx.y;
  for (int i = tid; i < 8*HH; i += 256){
    int si = i >> 10, k = i & 1023;
    h1s[si][k] = H1[(size_t)(s0+si)*BB*HH + (size_t)b*HH + k];
  }
  __syncthreads();
  {
    const int l = tid & 127, half = tid >> 7;
    const float4* er = (const float4*)(enc + ((size_t)l*BB + b)*HH + half*512);
    float a[8];
    #pragma unroll
    for (int s=0;s<8;s++) a[s]=0.f;
    for (int q=0;q<128;q++){
      float4 e = er[q];
      #pragma unroll
      for (int s=0;s<8;s++){
        const float4 h = *(const float4*)(&h1s[s][half*512 + q*4]);
        a[s] += h.x*e.x + h.y*e.y + h.z*e.z + h.w*e.w;
      }
    }
    #pragma unroll
    for (int s=0;s<8;s++) part[half][s][l] = a[s];
  }
  __syncthreads();
  for (int p = tid; p < 1024; p += 256){
    int s = p >> 7, l = p & 127;
    sc[s][l] = (part[0][s][l] + part[1][s][l]) * 0.03125f;
  }
  __syncthreads();
  {
    int s = tid >> 5, lid = tid & 31;
    float v0 = sc[s][lid], v1 = sc[s][lid+32], v2 = sc[s][lid+64], v3 = sc[s][lid+96];
    float m = fmaxf(fmaxf(v0,v1),fmaxf(v2,v3));
    for (int off=16; off>=1; off>>=1) m = fmaxf(m, __shfl_xor(m, off, 32));
    float e0=__expf(v0-m), e1=__expf(v1-m), e2=__expf(v2-m), e3=__expf(v3-m);
    float ssum = e0+e1+e2+e3;
    for (int off=16; off>=1; off>>=1) ssum += __shfl_xor(ssum, off, 32);
    float inv = 1.0f/ssum;
    sc[s][lid]=e0*inv; sc[s][lid+32]=e1*inv; sc[s][lid+64]=e2*inv; sc[s][lid+96]=e3*inv;
  }
  __syncthreads();
  {
    float acc[4][8];
    #pragma unroll
    for (int q=0;q<4;q++)
      #pragma unroll
      for (int s=0;s<8;s++) acc[q][s]=0.f;
    for (int l=0;l<128;l++){
      const float* er = enc + ((size_t)l*BB + b)*HH + tid;
      float a[8];
      #pragma unroll
      for (int s=0;s<8;s++) a[s] = sc[s][l];
      #pragma unroll
      for (int q=0;q<4;q++){
        float e = er[q*256];
        #pragma unroll
        for (int s=0;s<8;s++) acc[q][s] = fmaf(a[s], e, acc[q][s]);
      }
    }
    #pragma unroll
    for (int s=0;s<8;s++)
      #pragma unroll
      for (int q=0;q<4;q++)
        ctxs[s][tid + q*256] = acc[q][s];
  }
  __syncthreads();
  {
    const int w = tid >> 6, lane = tid & 63;
    const float tg = (float)ts[0];
    #pragma unroll
    for (int si=0; si<2; si++){
      const int s = (w<<1) + si;
      const int t = s0 + s;
      const int v = inp[b*LL + t];
      float acc = 0.f;
      #pragma unroll
      for (int q=0;q<16;q++){
        int k = lane + q*64;
        acc = fmaf(h1s[s][k], Wout[(size_t)k*VV + v], acc);
      }
      #pragma unroll
      for (int q=0;q<16;q++){
        int k = lane + q*64;
        acc = fmaf(ctxs[s][k], Wout[(size_t)(k+1024)*VV + v], acc);
      }
      acc = red64(acc);
      if (lane == 0){
        float logit = acc + bout[v];
        float p = 1.0f/(1.0f + expf(-logit));
        outp[b*LL + t] = p;
        float pc = fminf(fmaxf(p, 1e-12f), 1.0f - 1e-7f);
        bce[b*LL + t] = -(tg*logf(pc) + (1.0f-tg)*log1pf(-pc));
      }
    }
  }
}

__global__ void k_loss(const float* __restrict__ bce, float* __restrict__ out0){
  __shared__ float rbuf[256];
  int tid = threadIdx.x;
  float s = 0.f;
  for (int i = tid; i < 2048; i += 256) s += bce[i];
  rbuf[tid] = s; __syncthreads();
  for (int st=128; st>0; st>>=1){
    if (tid<st) rbuf[tid]+=rbuf[tid+st];
    __syncthreads();
  }
  if (tid==0) out0[0] = rbuf[0] * (1.0f/(2048.0f*16.0f));
}

extern "C" void kernel_launch(void* const* d_in, const int* in_sizes, int n_in,
                              void* d_out, int out_size, void* d_ws, size_t ws_size,
                              hipStream_t stream){
  (void)in_sizes; (void)n_in; (void)out_size; (void)ws_size;
  const int*   inp   = (const int*)d_in[0];
  const int*   ts    = (const int*)d_in[2];
  const float* emb   = (const float*)d_in[3];
  const float* encW  = (const float*)d_in[4];
  const float* encb  = (const float*)d_in[5];
  const float* Wih0  = (const float*)d_in[6];
  const float* Whh0  = (const float*)d_in[7];
  const float* bih0  = (const float*)d_in[8];
  const float* bhh0  = (const float*)d_in[9];
  const float* Wih1  = (const float*)d_in[10];
  const float* Whh1  = (const float*)d_in[11];
  const float* bih1  = (const float*)d_in[12];
  const float* bhh1  = (const float*)d_in[13];
  const float* Wout  = (const float*)d_in[14];
  const float* bout  = (const float*)d_in[15];
  float* out = (float*)d_out;

  float* ws      = (float*)d_ws;
  float* enc_out = ws;
  float* H0      = enc_out + 2097152;
  float* H1      = H0 + 2097152;
  float* GX1     = H1 + 2097152;     // unused hole (layout kept stable)
  float* CTX     = GX1 + 6291456;    // unused hole
  float* gx0     = CTX + 2097152;    // unused hole
  float* bceb    = gx0 + 3072;
  int*   rowidx  = (int*)(bceb + 2048);  // unused hole
  int*   flags   = rowidx + 2048;
  int*   go      = flags + 256*32;

  (void)hipMemsetAsync(flags, 0, (256*32 + 32)*sizeof(int), stream);
  k_gemm_enc<<<dim3(64,2),256,0,stream>>>(emb, inp, encW, encb, enc_out);

  const float* enclast = enc_out + (size_t)127*BB*HH;

  k_chains<<<NBLK,512,0,stream>>>(enclast, H0, H1, Whh0, Whh1, Wih0, Wih1, emb,
                                  bih0, bhh0, bhh1, bih1, flags, go);
  k_attn_logit<<<dim3(16,16),256,0,stream>>>(enc_out, H1, Wout, bout, inp, ts,
                                             out+1, bceb);
  k_loss<<<1,256,0,stream>>>(bceb, out);
}

// Round 21
// 1806.652 us; speedup vs baseline: 1.4165x; 1.4165x over previous
//
#include <hip/hip_runtime.h>
#include <math.h>

#define BB 16
#define LL 128
#define HH 1024
#define EE 512
#define VV 32000
#define G3 3072
#define NBLK 256

__device__ __forceinline__ float sigmoidf_(float x){ return 1.0f/(1.0f+expf(-x)); }

__device__ __forceinline__ float red64(float v){
  v += __shfl_xor(v, 1, 64); v += __shfl_xor(v, 2, 64);
  v += __shfl_xor(v, 4, 64); v += __shfl_xor(v, 8, 64);
  v += __shfl_xor(v, 16, 64); v += __shfl_xor(v, 32, 64);
  return v;
}
__device__ __forceinline__ float red32(float v){
  v += __shfl_xor(v, 1, 64); v += __shfl_xor(v, 2, 64);
  v += __shfl_xor(v, 4, 64); v += __shfl_xor(v, 8, 64);
  v += __shfl_xor(v, 16, 64);
  return v;
}

// Encoder GEMM with inline token lookup
__global__ __launch_bounds__(256) void k_gemm_enc(const float* __restrict__ emb, const int* __restrict__ inp,
                       const float* __restrict__ Bm, const float* __restrict__ bias,
                       float* __restrict__ C){
  __shared__ float As[32*EE];
  const int tid = threadIdx.x;
  const int r0 = blockIdx.x*32;
  const int c  = blockIdx.y*512 + (tid<<1);
  for (int i = tid; i < 32*EE; i += 256){
    int rr = i >> 9;
    int row = r0 + rr;
    int l = row >> 4, bb = row & 15;
    int tok = inp[bb*LL + l];
    int kk = i & 511;
    As[i] = emb[(size_t)tok*EE + kk];
  }
  __syncthreads();
  float2 acc[32];
  #pragma unroll
  for (int r=0;r<32;r++){ acc[r].x=0.f; acc[r].y=0.f; }
  for (int k=0;k<EE;k++){
    const float2 w = *(const float2*)(Bm + (size_t)k*HH + c);
    #pragma unroll
    for (int r=0;r<32;r++){
      float a = As[(r<<9)+k];
      acc[r].x = fmaf(a,w.x,acc[r].x);
      acc[r].y = fmaf(a,w.y,acc[r].y);
    }
  }
  const float2 bv = *(const float2*)(bias + c);
  #pragma unroll
  for (int r=0;r<32;r++){
    float x = tanhf(acc[r].x + bv.x), y = tanhf(acc[r].y + bv.y);
    *(float2*)(C + (size_t)(r0+r)*HH + c) = make_float2(x,y);
  }
}

// v11: R13 chain with A-phase first (early h0 store issue) + busy polls.
__global__ __launch_bounds__(512,1) void k_chains(
    const float* enclast, float* H0all, float* H1all,
    const float* __restrict__ Whh0, const float* __restrict__ Whh1,
    const float* __restrict__ Wih0, const float* __restrict__ Wih1,
    const float* __restrict__ emb,
    const float* __restrict__ bih0, const float* __restrict__ bhh0,
    const float* __restrict__ bhh1, const float* __restrict__ bih1,
    int* flags, int* go)
{
  __shared__ float w0l[12][1024];
  __shared__ float w1l[12][1024];
  __shared__ float wil[12][1024];
  __shared__ float gxbuf[16*12];
  const int tid  = threadIdx.x;
  const int jb   = blockIdx.x << 2;
  const int waveid = tid >> 6;
  const int cgA = waveid >> 2;
  const int bgA = waveid & 3;
  const int kgA = tid & 63;
  const int koffA = kgA << 2;
  const int b0A = bgA << 2;
  const int cgB = waveid >> 1;
  const int bgB = ((waveid & 1) << 1) | ((tid >> 5) & 1);
  const int kgB = tid & 31;
  const int koffB = kgB << 2;
  const int b0B = bgB << 2;
  const int mB  = cgB >> 1;

  const bool pwA = (kgA < 8);
  const int  jlA = (cgA << 1) + (kgA & 1);
  const int  jpA = jb + jlA;
  const int  biA = (kgA >> 1) & 3;
  const int  bA  = b0A + biA;
  const bool pwB = (cgB >= 2) && (kgB < 8);
  const int  jlB = ((cgB & 1) << 1) + (kgB & 1);
  const int  jpB = jb + jlB;
  const int  biB = (kgB >> 1) & 3;
  const int  bB  = b0B + biB;

  float g0r=0.f, g0z=0.f, g0n=0.f;
  {
    for (int idx = tid; idx < 1536; idx += 512){
      int g = idx >> 9, k = idx & 511;
      float4 a = *(const float4*)(Wih0 + (size_t)k*G3 + g*1024 + jb);
      w0l[g*4+0][k]=a.x; w0l[g*4+1][k]=a.y; w0l[g*4+2][k]=a.z; w0l[g*4+3][k]=a.w;
    }
    __syncthreads();
    const float* e1 = emb + EE;
    float ag[6];
    #pragma unroll
    for (int cl=0;cl<6;cl++) ag[cl]=0.f;
    #pragma unroll
    for (int u=0;u<2;u++){
      float4 e = *(const float4*)(e1 + u*256 + koffA);
      #pragma unroll
      for (int cl=0;cl<6;cl++){
        const int gc = ((cl>>1)<<2) + (cgA<<1) + (cl&1);
        const float4 w = *(const float4*)(&w0l[gc][u*256 + koffA]);
        float v = ag[cl];
        v=fmaf(w.x,e.x,v); v=fmaf(w.y,e.y,v); v=fmaf(w.z,e.z,v); v=fmaf(w.w,e.w,v);
        ag[cl]=v;
      }
    }
    #pragma unroll
    for (int cl=0;cl<6;cl++) ag[cl] = red64(ag[cl]);
    if (pwA){
      const int jj = kgA & 1;
      g0r = (jj ? ag[1] : ag[0]) + bih0[jpA];
      g0z = (jj ? ag[3] : ag[2]) + bih0[1024+jpA];
      g0n = (jj ? ag[5] : ag[4]) + bih0[2048+jpA];
    }
    __syncthreads();
  }

  for (int idx = tid; idx < 3072; idx += 512){
    int g = idx >> 10, k = idx & 1023;
    float4 a = *(const float4*)(Whh0 + (size_t)k*G3 + g*1024 + jb);
    w0l[g*4+0][k]=a.x; w0l[g*4+1][k]=a.y; w0l[g*4+2][k]=a.z; w0l[g*4+3][k]=a.w;
    float4 d = *(const float4*)(Whh1 + (size_t)k*G3 + g*1024 + jb);
    w1l[g*4+0][k]=d.x; w1l[g*4+1][k]=d.y; w1l[g*4+2][k]=d.z; w1l[g*4+3][k]=d.w;
    float4 e = *(const float4*)(Wih1 + (size_t)k*G3 + g*1024 + jb);
    wil[g*4+0][k]=e.x; wil[g*4+1][k]=e.y; wil[g*4+2][k]=e.z; wil[g*4+3][k]=e.w;
  }
  float b0rA=0.f,b0zA=0.f,b0nA=0.f;
  if (pwA){ b0rA = bhh0[jpA]; b0zA = bhh0[1024+jpA]; b0nA = bhh0[2048+jpA]; }
  float birB=0.f,bizB=0.f,binB=0.f,b1rB=0.f,b1zB=0.f,b1nB=0.f;
  if (pwB){
    birB = bih1[jpB]; bizB = bih1[1024+jpB]; binB = bih1[2048+jpB];
    b1rB = bhh1[jpB]; b1zB = bhh1[1024+jpB]; b1nB = bhh1[2048+jpB];
  }
  __syncthreads();

  const int myflag = (int)blockIdx.x * 32;

  for (int t = 0; t <= LL; ++t){
    // ---- wait(t): block-0 aggregator + single-go, busy polls ----
    if (t >= 1){
      if (blockIdx.x == 0){
        if (tid < 256){
          while (__hip_atomic_load(&flags[tid*32], __ATOMIC_RELAXED,
                                   __HIP_MEMORY_SCOPE_AGENT) < t) {}
        }
        __syncthreads();
        if (tid == 0)
          __hip_atomic_store(go, t, __ATOMIC_RELAXED, __HIP_MEMORY_SCOPE_AGENT);
      } else {
        if (tid == 0){
          while (__hip_atomic_load(go, __ATOMIC_RELAXED,
                                   __HIP_MEMORY_SCOPE_AGENT) < t) {}
        }
        __syncthreads();
      }
    }

    // ---- A(t): layer0 step t (FIRST: its stores drain under B's MAC) ----
    if (t < LL){
      const float* hp0 = (t==0) ? enclast : (H0all + (size_t)(t-1)*(BB*HH));
      float hprev0 = 0.f;
      if (pwA) hprev0 = hp0[(size_t)bA*HH + jpA];

      float acc0[6][4];
      #pragma unroll
      for (int cl=0;cl<6;cl++)
        #pragma unroll
        for (int bi=0;bi<4;bi++) acc0[cl][bi]=0.f;

      #pragma unroll
      for (int u=0;u<4;u++){
        float4 h4[4];
        #pragma unroll
        for (int bi=0;bi<4;bi++)
          h4[bi] = *(const float4*)(hp0 + (size_t)(b0A+bi)*HH + u*256 + koffA);
        #pragma unroll
        for (int cl=0;cl<6;cl++){
          const int gc = ((cl>>1)<<2) + (cgA<<1) + (cl&1);
          const float4 w = *(const float4*)(&w0l[gc][u*256 + koffA]);
          #pragma unroll
          for (int bi=0;bi<4;bi++){
            float v = acc0[cl][bi];
            v=fmaf(w.x,h4[bi].x,v); v=fmaf(w.y,h4[bi].y,v);
            v=fmaf(w.z,h4[bi].z,v); v=fmaf(w.w,h4[bi].w,v);
            acc0[cl][bi]=v;
          }
        }
      }
      #pragma unroll
      for (int cl=0;cl<6;cl++)
        #pragma unroll
        for (int bi=0;bi<4;bi++) acc0[cl][bi] = red64(acc0[cl][bi]);

      if (pwA){
        float ghr=0.f, ghz=0.f, ghn=0.f;
        #pragma unroll
        for (int jj=0;jj<2;jj++)
          #pragma unroll
          for (int ii=0;ii<4;ii++){
            bool sel = ((kgA&1)==jj) & (biA==ii);
            ghr = sel ? acc0[jj][ii]   : ghr;
            ghz = sel ? acc0[2+jj][ii] : ghz;
            ghn = sel ? acc0[4+jj][ii] : ghn;
          }
        float r = sigmoidf_(g0r + ghr + b0rA);
        float z = sigmoidf_(g0z + ghz + b0zA);
        float n = tanhf    (g0n + r*(ghn + b0nA));
        float hnew = (1.f-z)*n + z*hprev0;
        __hip_atomic_store((int*)&H0all[(size_t)t*(BB*HH) + (size_t)bA*HH + jpA],
                           __float_as_int(hnew),
                           __ATOMIC_RELAXED, __HIP_MEMORY_SCOPE_AGENT);
      }
    }

    // ---- B(t): gx1 = h0[t-1]@Wih1 ; layer1 step t-1 ----
    if (t >= 1){
      const float* hp0 = H0all + (size_t)(t-1)*(BB*HH);
      const float* hp1 = (t==1) ? enclast : (H1all + (size_t)(t-2)*(BB*HH));
      const float* hr  = mB ? hp1 : hp0;
      float hprev1 = 0.f;
      if (pwB) hprev1 = hp1[(size_t)bB*HH + jpB];

      float accB[6][4];
      #pragma unroll
      for (int cl=0;cl<6;cl++)
        #pragma unroll
        for (int bi=0;bi<4;bi++) accB[cl][bi]=0.f;

      #pragma unroll
      for (int u=0;u<8;u++){
        float4 h4[4];
        #pragma unroll
        for (int bi=0;bi<4;bi++)
          h4[bi] = *(const float4*)(hr + (size_t)(b0B+bi)*HH + u*128 + koffB);
        #pragma unroll
        for (int cl=0;cl<6;cl++){
          const int gc = ((cl>>1)<<2) + ((cgB&1)<<1) + (cl&1);
          const float4 w = mB ? *(const float4*)(&w1l[gc][u*128 + koffB])
                              : *(const float4*)(&wil[gc][u*128 + koffB]);
          #pragma unroll
          for (int bi=0;bi<4;bi++){
            float v = accB[cl][bi];
            v=fmaf(w.x,h4[bi].x,v); v=fmaf(w.y,h4[bi].y,v);
            v=fmaf(w.z,h4[bi].z,v); v=fmaf(w.w,h4[bi].w,v);
            accB[cl][bi]=v;
          }
        }
      }
      #pragma unroll
      for (int cl=0;cl<6;cl++)
        #pragma unroll
        for (int bi=0;bi<4;bi++) accB[cl][bi] = red32(accB[cl][bi]);

      if (mB == 0){
        #pragma unroll
        for (int cl=0;cl<6;cl++){
          if (kgB == cl){
            const int g = cl >> 1;
            const int jl = ((cgB&1)<<1) + (cl&1);
            #pragma unroll
            for (int bi=0;bi<4;bi++)
              gxbuf[(b0B+bi)*12 + g*4 + jl] = accB[cl][bi];
          }
        }
      }
      __syncthreads();
      if (pwB){
        float ghr=0.f, ghz=0.f, ghn=0.f;
        #pragma unroll
        for (int jj=0;jj<2;jj++)
          #pragma unroll
          for (int ii=0;ii<4;ii++){
            bool sel = ((kgB&1)==jj) & (biB==ii);
            ghr = sel ? accB[jj][ii]   : ghr;
            ghz = sel ? accB[2+jj][ii] : ghz;
            ghn = sel ? accB[4+jj][ii] : ghn;
          }
        float gxr = gxbuf[bB*12 + 0*4 + jlB];
        float gxz = gxbuf[bB*12 + 1*4 + jlB];
        float gxn = gxbuf[bB*12 + 2*4 + jlB];
        float r = sigmoidf_(gxr + birB + ghr + b1rB);
        float z = sigmoidf_(gxz + bizB + ghz + b1zB);
        float n = tanhf    (gxn + binB + r*(ghn + b1nB));
        float hnew = (1.f-z)*n + z*hprev1;
        __hip_atomic_store((int*)&H1all[(size_t)(t-1)*(BB*HH) + (size_t)bB*HH + jpB],
                           __float_as_int(hnew),
                           __ATOMIC_RELAXED, __HIP_MEMORY_SCOPE_AGENT);
      }
    }

    if (t < LL){
      asm volatile("s_waitcnt vmcnt(0)" ::: "memory");
      __syncthreads();
      if (tid == 0)
        __hip_atomic_store(&flags[myflag], t+1,
                           __ATOMIC_RELAXED, __HIP_MEMORY_SCOPE_AGENT);
    }
  }
}

// Fused attention + gathered logit: ctx never leaves LDS.
__global__ __launch_bounds__(256) void k_attn_logit(const float* __restrict__ enc,
                       const float* __restrict__ H1,
                       const float* __restrict__ Wout, const float* __restrict__ bout,
                       const int* __restrict__ inp, const int* __restrict__ ts,
                       float* __restrict__ outp, float* __restrict__ bce){
  __shared__ float h1s[8][HH];
  __shared__ float ctxs[8][HH];
  __shared__ float sc[8][LL];
  __shared__ float part[2][8][LL];
  const int tid = threadIdx.x;
  const int s0 = blockIdx.x*8, b = blockIdx.y;
  for (int i = tid; i < 8*HH; i += 256){
    int si = i >> 10, k = i & 1023;
    h1s[si][k] = H1[(size_t)(s0+si)*BB*HH + (size_t)b*HH + k];
  }
  __syncthreads();
  {
    const int l = tid & 127, half = tid >> 7;
    const float4* er = (const float4*)(enc + ((size_t)l*BB + b)*HH + half*512);
    float a[8];
    #pragma unroll
    for (int s=0;s<8;s++) a[s]=0.f;
    for (int q=0;q<128;q++){
      float4 e = er[q];
      #pragma unroll
      for (int s=0;s<8;s++){
        const float4 h = *(const float4*)(&h1s[s][half*512 + q*4]);
        a[s] += h.x*e.x + h.y*e.y + h.z*e.z + h.w*e.w;
      }
    }
    #pragma unroll
    for (int s=0;s<8;s++) part[half][s][l] = a[s];
  }
  __syncthreads();
  for (int p = tid; p < 1024; p += 256){
    int s = p >> 7, l = p & 127;
    sc[s][l] = (part[0][s][l] + part[1][s][l]) * 0.03125f;
  }
  __syncthreads();
  {
    int s = tid >> 5, lid = tid & 31;
    float v0 = sc[s][lid], v1 = sc[s][lid+32], v2 = sc[s][lid+64], v3 = sc[s][lid+96];
    float m = fmaxf(fmaxf(v0,v1),fmaxf(v2,v3));
    for (int off=16; off>=1; off>>=1) m = fmaxf(m, __shfl_xor(m, off, 32));
    float e0=__expf(v0-m), e1=__expf(v1-m), e2=__expf(v2-m), e3=__expf(v3-m);
    float ssum = e0+e1+e2+e3;
    for (int off=16; off>=1; off>>=1) ssum += __shfl_xor(ssum, off, 32);
    float inv = 1.0f/ssum;
    sc[s][lid]=e0*inv; sc[s][lid+32]=e1*inv; sc[s][lid+64]=e2*inv; sc[s][lid+96]=e3*inv;
  }
  __syncthreads();
  {
    float acc[4][8];
    #pragma unroll
    for (int q=0;q<4;q++)
      #pragma unroll
      for (int s=0;s<8;s++) acc[q][s]=0.f;
    for (int l=0;l<128;l++){
      const float* er = enc + ((size_t)l*BB + b)*HH + tid;
      float a[8];
      #pragma unroll
      for (int s=0;s<8;s++) a[s] = sc[s][l];
      #pragma unroll
      for (int q=0;q<4;q++){
        float e = er[q*256];
        #pragma unroll
        for (int s=0;s<8;s++) acc[q][s] = fmaf(a[s], e, acc[q][s]);
      }
    }
    #pragma unroll
    for (int s=0;s<8;s++)
      #pragma unroll
      for (int q=0;q<4;q++)
        ctxs[s][tid + q*256] = acc[q][s];
  }
  __syncthreads();
  {
    const int w = tid >> 6, lane = tid & 63;
    const float tg = (float)ts[0];
    #pragma unroll
    for (int si=0; si<2; si++){
      const int s = (w<<1) + si;
      const int t = s0 + s;
      const int v = inp[b*LL + t];
      float acc = 0.f;
      #pragma unroll
      for (int q=0;q<16;q++){
        int k = lane + q*64;
        acc = fmaf(h1s[s][k], Wout[(size_t)k*VV + v], acc);
      }
      #pragma unroll
      for (int q=0;q<16;q++){
        int k = lane + q*64;
        acc = fmaf(ctxs[s][k], Wout[(size_t)(k+1024)*VV + v], acc);
      }
      acc = red64(acc);
      if (lane == 0){
        float logit = acc + bout[v];
        float p = 1.0f/(1.0f + expf(-logit));
        outp[b*LL + t] = p;
        float pc = fminf(fmaxf(p, 1e-12f), 1.0f - 1e-7f);
        bce[b*LL + t] = -(tg*logf(pc) + (1.0f-tg)*log1pf(-pc));
      }
    }
  }
}

__global__ void k_loss(const float* __restrict__ bce, float* __restrict__ out0){
  __shared__ float rbuf[256];
  int tid = threadIdx.x;
  float s = 0.f;
  for (int i = tid; i < 2048; i += 256) s += bce[i];
  rbuf[tid] = s; __syncthreads();
  for (int st=128; st>0; st>>=1){
    if (tid<st) rbuf[tid]+=rbuf[tid+st];
    __syncthreads();
  }
  if (tid==0) out0[0] = rbuf[0] * (1.0f/(2048.0f*16.0f));
}

extern "C" void kernel_launch(void* const* d_in, const int* in_sizes, int n_in,
                              void* d_out, int out_size, void* d_ws, size_t ws_size,
                              hipStream_t stream){
  (void)in_sizes; (void)n_in; (void)out_size; (void)ws_size;
  const int*   inp   = (const int*)d_in[0];
  const int*   ts    = (const int*)d_in[2];
  const float* emb   = (const float*)d_in[3];
  const float* encW  = (const float*)d_in[4];
  const float* encb  = (const float*)d_in[5];
  const float* Wih0  = (const float*)d_in[6];
  const float* Whh0  = (const float*)d_in[7];
  const float* bih0  = (const float*)d_in[8];
  const float* bhh0  = (const float*)d_in[9];
  const float* Wih1  = (const float*)d_in[10];
  const float* Whh1  = (const float*)d_in[11];
  const float* bih1  = (const float*)d_in[12];
  const float* bhh1  = (const float*)d_in[13];
  const float* Wout  = (const float*)d_in[14];
  const float* bout  = (const float*)d_in[15];
  float* out = (float*)d_out;

  float* ws      = (float*)d_ws;
  float* enc_out = ws;
  float* H0      = enc_out + 2097152;
  float* H1      = H0 + 2097152;
  float* GX1     = H1 + 2097152;     // unused hole (layout kept stable)
  float* CTX     = GX1 + 6291456;    // unused hole
  float* gx0     = CTX + 2097152;    // unused hole
  float* bceb    = gx0 + 3072;
  int*   rowidx  = (int*)(bceb + 2048);  // unused hole
  int*   flags   = rowidx + 2048;
  int*   go      = flags + 256*32;

  (void)hipMemsetAsync(flags, 0, (256*32 + 32)*sizeof(int), stream);
  k_gemm_enc<<<dim3(64,2),256,0,stream>>>(emb, inp, encW, encb, enc_out);

  const float* enclast = enc_out + (size_t)127*BB*HH;

  k_chains<<<NBLK,512,0,stream>>>(enclast, H0, H1, Whh0, Whh1, Wih0, Wih1, emb,
                                  bih0, bhh0, bhh1, bih1, flags, go);
  k_attn_logit<<<dim3(16,16),256,0,stream>>>(enc_out, H1, Wout, bout, inp, ts,
                                             out+1, bceb);
  k_loss<<<1,256,0,stream>>>(bceb, out);
}